// Round 1
// baseline (399.591 us; speedup 1.0000x reference)
//
#include <hip/hip_runtime.h>
#include <math.h>

#define NN 50000
#define NE 500000
#define NF 128
#define NO 16
#define SCAN_B 1024

// ---------------- graph preprocessing ----------------

__global__ void k_deg_count(const int* __restrict__ dst, const float* __restrict__ ew,
                            float* __restrict__ deg, int* __restrict__ counts, int E) {
    int e = blockIdx.x * blockDim.x + threadIdx.x;
    if (e < E) {
        int d = dst[e];
        atomicAdd(&deg[d], ew[e]);
        atomicAdd(&counts[d], 1);
    }
}

__global__ void k_dinv(float* __restrict__ deg, int N) {
    int i = blockIdx.x * blockDim.x + threadIdx.x;
    if (i < N) {
        float d = deg[i] + 1.0f;      // self-loop weight 1
        deg[i] = rsqrtf(d);           // in-place -> dinv
    }
}

// exclusive scan of counts -> offs (3-phase)
__global__ void k_scan1(const int* __restrict__ counts, int* __restrict__ offs,
                        int* __restrict__ bsums, int N) {
    __shared__ int s[SCAN_B];
    int t = threadIdx.x;
    int i = blockIdx.x * SCAN_B + t;
    int c = (i < N) ? counts[i] : 0;
    s[t] = c;
    __syncthreads();
    for (int off = 1; off < SCAN_B; off <<= 1) {
        int x = (t >= off) ? s[t - off] : 0;
        __syncthreads();
        s[t] += x;
        __syncthreads();
    }
    if (i < N) offs[i] = s[t] - c;            // exclusive within block
    if (t == SCAN_B - 1) bsums[blockIdx.x] = s[t];
}

__global__ void k_scan2(int* __restrict__ bsums, int NB) {
    if (threadIdx.x == 0 && blockIdx.x == 0) {
        int run = 0;
        for (int i = 0; i < NB; ++i) { int c = bsums[i]; bsums[i] = run; run += c; }
    }
}

__global__ void k_scan3(int* __restrict__ offs, const int* __restrict__ bsums,
                        int* __restrict__ cursor, int N, int E) {
    int i = blockIdx.x * blockDim.x + threadIdx.x;
    if (i < N) {
        int v = offs[i] + bsums[i >> 10];
        offs[i] = v;
        cursor[i] = v;
    } else if (i == N) {
        offs[N] = E;
    }
}

__global__ void k_fill(const int* __restrict__ src, const int* __restrict__ dst,
                       const float* __restrict__ ew, const float* __restrict__ dinv,
                       int* __restrict__ cursor, int* __restrict__ src_s,
                       float* __restrict__ norm_s, int E) {
    int e = blockIdx.x * blockDim.x + threadIdx.x;
    if (e < E) {
        int d = dst[e], s = src[e];
        int p = atomicAdd(&cursor[d], 1);
        src_s[p] = s;
        norm_s[p] = dinv[s] * ew[e] * dinv[d];
    }
}

// ---------------- GEMM: Y[M,128] = X[M,128] @ W[128,128] ----------------
// block: 256 thr, tile 64 rows x 128 cols, k-chunks of 64, thread tile 4x8.
__global__ __launch_bounds__(256) void k_gemm128(const float* __restrict__ X,
                                                 const float* __restrict__ W,
                                                 float* __restrict__ Y, int M) {
    __shared__ float Xs[64][68];     // padded (68) so float4 writes stay 16B-aligned
    __shared__ float Ws[64][128];
    const int tid = threadIdx.x;
    const int tx = tid & 15;         // col group (8 cols each)
    const int ty = tid >> 4;         // row group (4 rows each)
    const int r0g = blockIdx.x * 64;

    float acc[4][8];
#pragma unroll
    for (int i = 0; i < 4; ++i)
#pragma unroll
        for (int j = 0; j < 8; ++j) acc[i][j] = 0.0f;

    for (int kc = 0; kc < 128; kc += 64) {
        // load X tile 64x64 (clamped rows; stores are guarded later)
        {
            int rr = tid >> 4;       // 0..15
            int k4 = tid & 15;       // 0..15 float4 within k-chunk
#pragma unroll
            for (int it = 0; it < 4; ++it) {
                int row = it * 16 + rr;
                int grow = r0g + row; if (grow > M - 1) grow = M - 1;
                float4 v = *(const float4*)(X + (size_t)grow * NF + kc + k4 * 4);
                *(float4*)(&Xs[row][k4 * 4]) = v;
            }
        }
        // load W chunk 64x128
        {
            int kk0 = tid >> 5;      // 0..7
            int c4  = tid & 31;      // 0..31
#pragma unroll
            for (int it = 0; it < 8; ++it) {
                int kk = it * 8 + kk0;
                float4 v = *(const float4*)(W + (size_t)(kc + kk) * NF + c4 * 4);
                *(float4*)(&Ws[kk][c4 * 4]) = v;
            }
        }
        __syncthreads();

#pragma unroll 8
        for (int k = 0; k < 64; ++k) {
            float a0 = Xs[ty * 4 + 0][k];
            float a1 = Xs[ty * 4 + 1][k];
            float a2 = Xs[ty * 4 + 2][k];
            float a3 = Xs[ty * 4 + 3][k];
            float4 b0 = *(const float4*)(&Ws[k][tx * 8]);
            float4 b1 = *(const float4*)(&Ws[k][tx * 8 + 4]);
            float bb[8] = {b0.x, b0.y, b0.z, b0.w, b1.x, b1.y, b1.z, b1.w};
#pragma unroll
            for (int j = 0; j < 8; ++j) {
                acc[0][j] = fmaf(a0, bb[j], acc[0][j]);
                acc[1][j] = fmaf(a1, bb[j], acc[1][j]);
                acc[2][j] = fmaf(a2, bb[j], acc[2][j]);
                acc[3][j] = fmaf(a3, bb[j], acc[3][j]);
            }
        }
        __syncthreads();
    }

#pragma unroll
    for (int i = 0; i < 4; ++i) {
        int row = r0g + ty * 4 + i;
        if (row < M) {
            float4 v0 = {acc[i][0], acc[i][1], acc[i][2], acc[i][3]};
            float4 v1 = {acc[i][4], acc[i][5], acc[i][6], acc[i][7]};
            *(float4*)(Y + (size_t)row * NF + tx * 8)     = v0;
            *(float4*)(Y + (size_t)row * NF + tx * 8 + 4) = v1;
        }
    }
}

// ---------------- aggregation, 128-wide: out = [relu](agg + selfloop + b) ----------------
__global__ __launch_bounds__(128) void k_agg128(const float* __restrict__ xw,
                                                const float* __restrict__ dinv,
                                                const int* __restrict__ offs,
                                                const int* __restrict__ src_s,
                                                const float* __restrict__ norm_s,
                                                const float* __restrict__ bias,
                                                float* __restrict__ out, int relu) {
    int n = blockIdx.x;
    int f = threadIdx.x;
    float di = dinv[n];
    float acc = xw[(size_t)n * NF + f] * (di * di);
    int s = offs[n], e = offs[n + 1];
    for (int j = s; j < e; ++j) {
        int sn = src_s[j];
        float w = norm_s[j];
        acc = fmaf(xw[(size_t)sn * NF + f], w, acc);
    }
    acc += bias[f];
    if (relu) acc = fmaxf(acc, 0.0f);
    out[(size_t)n * NF + f] = acc;
}

// ---------------- GEMM: Y[M,16] = H[M,128] @ W3[128,16] ----------------
__global__ __launch_bounds__(256) void k_gemm16(const float* __restrict__ H,
                                                const float* __restrict__ W3,
                                                float* __restrict__ Y, int M) {
    __shared__ float Wl[NF * NO];        // 8 KB
    __shared__ float Hs[16 * 132];       // 16 rows, padded stride 132
    int tid = threadIdx.x;
    for (int i = tid; i < NF * NO; i += 256) Wl[i] = W3[i];
    int n0 = blockIdx.x * 16;
#pragma unroll
    for (int it = 0; it < 2; ++it) {
        int idx = tid + it * 256;        // 0..511
        int r = idx >> 5, f4 = idx & 31;
        int gr = n0 + r; if (gr > M - 1) gr = M - 1;
        *(float4*)(&Hs[r * 132 + f4 * 4]) = *(const float4*)(H + (size_t)gr * NF + f4 * 4);
    }
    __syncthreads();
    int ln = tid >> 4, c = tid & 15;
    float acc = 0.0f;
#pragma unroll 8
    for (int k = 0; k < NF; ++k) acc = fmaf(Hs[ln * 132 + k], Wl[k * NO + c], acc);
    int n = n0 + ln;
    if (n < M) Y[(size_t)n * NO + c] = acc;
}

// ---------------- final aggregation (16-wide) + bias + log_softmax ----------------
__global__ __launch_bounds__(256) void k_agg16_ls(const float* __restrict__ xw,
                                                  const float* __restrict__ dinv,
                                                  const int* __restrict__ offs,
                                                  const int* __restrict__ src_s,
                                                  const float* __restrict__ norm_s,
                                                  const float* __restrict__ bias,
                                                  float* __restrict__ out) {
    int tid = threadIdx.x;
    int ln = tid >> 4, c = tid & 15;
    int n = blockIdx.x * 16 + ln;        // grid sized exactly: no guard needed
    float di = dinv[n];
    float acc = xw[(size_t)n * NO + c] * (di * di);
    int s = offs[n], e = offs[n + 1];
    for (int j = s; j < e; ++j) {
        acc = fmaf(xw[(size_t)src_s[j] * NO + c], norm_s[j], acc);
    }
    acc += bias[c];
    // log_softmax across the 16 lanes of this node
    float m = acc;
#pragma unroll
    for (int off = 8; off > 0; off >>= 1) m = fmaxf(m, __shfl_xor(m, off, 16));
    float ex = expf(acc - m);
    float ss = ex;
#pragma unroll
    for (int off = 8; off > 0; off >>= 1) ss += __shfl_xor(ss, off, 16);
    out[(size_t)n * NO + c] = acc - m - logf(ss);
}

// ---------------- launch ----------------

extern "C" void kernel_launch(void* const* d_in, const int* in_sizes, int n_in,
                              void* d_out, int out_size, void* d_ws, size_t ws_size,
                              hipStream_t stream) {
    const float* x   = (const float*)d_in[0];
    const int*   esrc= (const int*)  d_in[1];
    const int*   edst= (const int*)  d_in[2];
    const float* ew  = (const float*)d_in[3];
    const float* W1  = (const float*)d_in[4];
    const float* b1  = (const float*)d_in[5];
    const float* W2  = (const float*)d_in[6];
    const float* b2  = (const float*)d_in[7];
    const float* W3  = (const float*)d_in[8];
    const float* b3  = (const float*)d_in[9];
    float* out = (float*)d_out;

    // workspace carve
    char* p = (char*)d_ws;
    float* xw     = (float*)p; p += (size_t)NN * NF * 4;   // 25.6 MB
    float* h      = (float*)p; p += (size_t)NN * NF * 4;   // 25.6 MB
    float* xw3    = (float*)p; p += (size_t)NN * NO * 4;   // 3.2 MB
    float* dinv   = (float*)p; p += (size_t)NN * 4;        // deg -> dinv in place
    float* norm_s = (float*)p; p += (size_t)NE * 4;
    int*   src_s  = (int*)p;   p += (size_t)NE * 4;
    int*   counts = (int*)p;   p += (size_t)NN * 4;
    int*   offs   = (int*)p;   p += (size_t)(NN + 1) * 4;
    int*   cursor = (int*)p;   p += (size_t)NN * 4;
    int*   bsums  = (int*)p;   p += 256;

    const int NB = (NN + SCAN_B - 1) / SCAN_B;   // 49

    hipMemsetAsync(dinv,   0, (size_t)NN * 4, stream);
    hipMemsetAsync(counts, 0, (size_t)NN * 4, stream);

    k_deg_count<<<(NE + 255) / 256, 256, 0, stream>>>(edst, ew, dinv, counts, NE);
    k_dinv<<<(NN + 255) / 256, 256, 0, stream>>>(dinv, NN);
    k_scan1<<<NB, SCAN_B, 0, stream>>>(counts, offs, bsums, NN);
    k_scan2<<<1, 64, 0, stream>>>(bsums, NB);
    k_scan3<<<(NN + 256) / 256, 256, 0, stream>>>(offs, bsums, cursor, NN, NE);
    k_fill<<<(NE + 255) / 256, 256, 0, stream>>>(esrc, edst, ew, dinv, cursor, src_s, norm_s, NE);

    // layer 1
    k_gemm128<<<(NN + 63) / 64, 256, 0, stream>>>(x, W1, xw, NN);
    k_agg128<<<NN, 128, 0, stream>>>(xw, dinv, offs, src_s, norm_s, b1, h, 1);
    // layer 2
    k_gemm128<<<(NN + 63) / 64, 256, 0, stream>>>(h, W2, xw, NN);
    k_agg128<<<NN, 128, 0, stream>>>(xw, dinv, offs, src_s, norm_s, b2, h, 1);
    // layer 3
    k_gemm16<<<(NN + 15) / 16, 256, 0, stream>>>(h, W3, xw3, NN);
    k_agg16_ls<<<NN / 16, 256, 0, stream>>>(xw3, dinv, offs, src_s, norm_s, b3, out);
}

// Round 2
// 326.887 us; speedup vs baseline: 1.2224x; 1.2224x over previous
//
#include <hip/hip_runtime.h>
#include <math.h>

#define NN 50000
#define NE 500000
#define NF 128
#define NO 16
#define SCAN_B 1024

typedef __attribute__((ext_vector_type(8))) _Float16 half8;

// ---------------- graph preprocessing ----------------

__global__ void k_deg_count(const int* __restrict__ dst, const float* __restrict__ ew,
                            float* __restrict__ deg, int* __restrict__ counts, int E) {
    int e = blockIdx.x * blockDim.x + threadIdx.x;
    if (e < E) {
        int d = dst[e];
        atomicAdd(&deg[d], ew[e]);
        atomicAdd(&counts[d], 1);
    }
}

__global__ void k_dinv(float* __restrict__ deg, int N) {
    int i = blockIdx.x * blockDim.x + threadIdx.x;
    if (i < N) {
        float d = deg[i] + 1.0f;      // self-loop weight 1
        deg[i] = rsqrtf(d);           // in-place -> dinv
    }
}

// exclusive scan of counts -> offs (3-phase)
__global__ void k_scan1(const int* __restrict__ counts, int* __restrict__ offs,
                        int* __restrict__ bsums, int N) {
    __shared__ int s[SCAN_B];
    int t = threadIdx.x;
    int i = blockIdx.x * SCAN_B + t;
    int c = (i < N) ? counts[i] : 0;
    s[t] = c;
    __syncthreads();
    for (int off = 1; off < SCAN_B; off <<= 1) {
        int x = (t >= off) ? s[t - off] : 0;
        __syncthreads();
        s[t] += x;
        __syncthreads();
    }
    if (i < N) offs[i] = s[t] - c;            // exclusive within block
    if (t == SCAN_B - 1) bsums[blockIdx.x] = s[t];
}

__global__ void k_scan2(int* __restrict__ bsums, int NB) {
    if (threadIdx.x == 0 && blockIdx.x == 0) {
        int run = 0;
        for (int i = 0; i < NB; ++i) { int c = bsums[i]; bsums[i] = run; run += c; }
    }
}

__global__ void k_scan3(int* __restrict__ offs, const int* __restrict__ bsums,
                        int* __restrict__ cursor, int N, int E) {
    int i = blockIdx.x * blockDim.x + threadIdx.x;
    if (i < N) {
        int v = offs[i] + bsums[i >> 10];
        offs[i] = v;
        cursor[i] = v;
    } else if (i == N) {
        offs[N] = E;
    }
}

__global__ void k_fill(const int* __restrict__ src, const int* __restrict__ dst,
                       const float* __restrict__ ew, const float* __restrict__ dinv,
                       int* __restrict__ cursor, int* __restrict__ src_s,
                       float* __restrict__ norm_s, int E) {
    int e = blockIdx.x * blockDim.x + threadIdx.x;
    if (e < E) {
        int d = dst[e], s = src[e];
        int p = atomicAdd(&cursor[d], 1);
        src_s[p] = s;
        norm_s[p] = dinv[s] * ew[e] * dinv[d];
    }
}

// ---------------- GEMM: Y[M,128](fp16) = X[M,128](fp32) @ W[128,128] ----------------
__global__ __launch_bounds__(256) void k_gemm128(const float* __restrict__ X,
                                                 const float* __restrict__ W,
                                                 _Float16* __restrict__ Y, int M) {
    __shared__ float Xs[64][68];
    __shared__ float Ws[64][128];
    const int tid = threadIdx.x;
    const int tx = tid & 15;
    const int ty = tid >> 4;
    const int r0g = blockIdx.x * 64;

    float acc[4][8];
#pragma unroll
    for (int i = 0; i < 4; ++i)
#pragma unroll
        for (int j = 0; j < 8; ++j) acc[i][j] = 0.0f;

    for (int kc = 0; kc < 128; kc += 64) {
        {
            int rr = tid >> 4;
            int k4 = tid & 15;
#pragma unroll
            for (int it = 0; it < 4; ++it) {
                int row = it * 16 + rr;
                int grow = r0g + row; if (grow > M - 1) grow = M - 1;
                float4 v = *(const float4*)(X + (size_t)grow * NF + kc + k4 * 4);
                *(float4*)(&Xs[row][k4 * 4]) = v;
            }
        }
        {
            int kk0 = tid >> 5;
            int c4  = tid & 31;
#pragma unroll
            for (int it = 0; it < 8; ++it) {
                int kk = it * 8 + kk0;
                float4 v = *(const float4*)(W + (size_t)(kc + kk) * NF + c4 * 4);
                *(float4*)(&Ws[kk][c4 * 4]) = v;
            }
        }
        __syncthreads();

#pragma unroll 8
        for (int k = 0; k < 64; ++k) {
            float a0 = Xs[ty * 4 + 0][k];
            float a1 = Xs[ty * 4 + 1][k];
            float a2 = Xs[ty * 4 + 2][k];
            float a3 = Xs[ty * 4 + 3][k];
            float4 b0 = *(const float4*)(&Ws[k][tx * 8]);
            float4 b1 = *(const float4*)(&Ws[k][tx * 8 + 4]);
            float bb[8] = {b0.x, b0.y, b0.z, b0.w, b1.x, b1.y, b1.z, b1.w};
#pragma unroll
            for (int j = 0; j < 8; ++j) {
                acc[0][j] = fmaf(a0, bb[j], acc[0][j]);
                acc[1][j] = fmaf(a1, bb[j], acc[1][j]);
                acc[2][j] = fmaf(a2, bb[j], acc[2][j]);
                acc[3][j] = fmaf(a3, bb[j], acc[3][j]);
            }
        }
        __syncthreads();
    }

#pragma unroll
    for (int i = 0; i < 4; ++i) {
        int row = r0g + ty * 4 + i;
        if (row < M) {
            half8 hv;
#pragma unroll
            for (int j = 0; j < 8; ++j) hv[j] = (_Float16)acc[i][j];
            *(half8*)(Y + (size_t)row * NF + tx * 8) = hv;
        }
    }
}

// ---------------- aggregation, 128-wide, fp16 gather table ----------------
// 1 wave (64 lanes) per node, 4 nodes per 256-block; lane handles 2 features.
__global__ __launch_bounds__(256) void k_agg128h(const _Float16* __restrict__ xw,
                                                 const float* __restrict__ dinv,
                                                 const int* __restrict__ offs,
                                                 const int* __restrict__ src_s,
                                                 const float* __restrict__ norm_s,
                                                 const float* __restrict__ bias,
                                                 float* __restrict__ out, int relu) {
    const int tid = threadIdx.x;
    const int ln = tid & 63;
    int n = __builtin_amdgcn_readfirstlane(blockIdx.x * 4 + (tid >> 6));

    union CV { unsigned int u; _Float16 h[2]; };

    float di = dinv[n];
    CV sv; sv.u = *(const unsigned int*)(xw + (size_t)n * NF + ln * 2);
    float acc0 = (float)sv.h[0] * (di * di);
    float acc1 = (float)sv.h[1] * (di * di);

    int s = offs[n], e = offs[n + 1];
    int j = s;
    for (; j + 1 < e; j += 2) {
        int s0 = src_s[j], s1 = src_s[j + 1];
        float w0 = norm_s[j], w1 = norm_s[j + 1];
        CV u0, u1;
        u0.u = *(const unsigned int*)(xw + (size_t)s0 * NF + ln * 2);
        u1.u = *(const unsigned int*)(xw + (size_t)s1 * NF + ln * 2);
        acc0 = fmaf((float)u0.h[0], w0, acc0);
        acc1 = fmaf((float)u0.h[1], w0, acc1);
        acc0 = fmaf((float)u1.h[0], w1, acc0);
        acc1 = fmaf((float)u1.h[1], w1, acc1);
    }
    if (j < e) {
        int s0 = src_s[j];
        float w0 = norm_s[j];
        CV u0; u0.u = *(const unsigned int*)(xw + (size_t)s0 * NF + ln * 2);
        acc0 = fmaf((float)u0.h[0], w0, acc0);
        acc1 = fmaf((float)u0.h[1], w0, acc1);
    }
    acc0 += bias[ln * 2];
    acc1 += bias[ln * 2 + 1];
    if (relu) { acc0 = fmaxf(acc0, 0.0f); acc1 = fmaxf(acc1, 0.0f); }
    float2 o = {acc0, acc1};
    *(float2*)(out + (size_t)n * NF + ln * 2) = o;
}

// ---------------- GEMM: Y[M,16] = H[M,128] @ W3[128,16] ----------------
__global__ __launch_bounds__(256) void k_gemm16(const float* __restrict__ H,
                                                const float* __restrict__ W3,
                                                float* __restrict__ Y, int M) {
    __shared__ float Wl[NF * NO];
    __shared__ float Hs[16 * 132];
    int tid = threadIdx.x;
    for (int i = tid; i < NF * NO; i += 256) Wl[i] = W3[i];
    int n0 = blockIdx.x * 16;
#pragma unroll
    for (int it = 0; it < 2; ++it) {
        int idx = tid + it * 256;
        int r = idx >> 5, f4 = idx & 31;
        int gr = n0 + r; if (gr > M - 1) gr = M - 1;
        *(float4*)(&Hs[r * 132 + f4 * 4]) = *(const float4*)(H + (size_t)gr * NF + f4 * 4);
    }
    __syncthreads();
    int ln = tid >> 4, c = tid & 15;
    float acc = 0.0f;
#pragma unroll 8
    for (int k = 0; k < NF; ++k) acc = fmaf(Hs[ln * 132 + k], Wl[k * NO + c], acc);
    int n = n0 + ln;
    if (n < M) Y[(size_t)n * NO + c] = acc;
}

// ---------------- final aggregation (16-wide) + bias + log_softmax ----------------
__global__ __launch_bounds__(256) void k_agg16_ls(const float* __restrict__ xw,
                                                  const float* __restrict__ dinv,
                                                  const int* __restrict__ offs,
                                                  const int* __restrict__ src_s,
                                                  const float* __restrict__ norm_s,
                                                  const float* __restrict__ bias,
                                                  float* __restrict__ out) {
    int tid = threadIdx.x;
    int ln = tid >> 4, c = tid & 15;
    int n = blockIdx.x * 16 + ln;
    float di = dinv[n];
    float acc = xw[(size_t)n * NO + c] * (di * di);
    int s = offs[n], e = offs[n + 1];
    for (int j = s; j < e; ++j) {
        acc = fmaf(xw[(size_t)src_s[j] * NO + c], norm_s[j], acc);
    }
    acc += bias[c];
    float m = acc;
#pragma unroll
    for (int off = 8; off > 0; off >>= 1) m = fmaxf(m, __shfl_xor(m, off, 16));
    float ex = expf(acc - m);
    float ss = ex;
#pragma unroll
    for (int off = 8; off > 0; off >>= 1) ss += __shfl_xor(ss, off, 16);
    out[(size_t)n * NO + c] = acc - m - logf(ss);
}

// ---------------- launch ----------------

extern "C" void kernel_launch(void* const* d_in, const int* in_sizes, int n_in,
                              void* d_out, int out_size, void* d_ws, size_t ws_size,
                              hipStream_t stream) {
    const float* x   = (const float*)d_in[0];
    const int*   esrc= (const int*)  d_in[1];
    const int*   edst= (const int*)  d_in[2];
    const float* ew  = (const float*)d_in[3];
    const float* W1  = (const float*)d_in[4];
    const float* b1  = (const float*)d_in[5];
    const float* W2  = (const float*)d_in[6];
    const float* b2  = (const float*)d_in[7];
    const float* W3  = (const float*)d_in[8];
    const float* b3  = (const float*)d_in[9];
    float* out = (float*)d_out;

    // workspace carve
    char* p = (char*)d_ws;
    _Float16* xw  = (_Float16*)p; p += (size_t)NN * NF * 2;  // 12.8 MB fp16
    float* h      = (float*)p; p += (size_t)NN * NF * 4;     // 25.6 MB
    float* xw3    = (float*)p; p += (size_t)NN * NO * 4;     // 3.2 MB
    float* dinv   = (float*)p; p += (size_t)NN * 4;
    float* norm_s = (float*)p; p += (size_t)NE * 4;
    int*   src_s  = (int*)p;   p += (size_t)NE * 4;
    int*   counts = (int*)p;   p += (size_t)NN * 4;
    int*   offs   = (int*)p;   p += (size_t)(NN + 1) * 4;
    int*   cursor = (int*)p;   p += (size_t)NN * 4;
    int*   bsums  = (int*)p;   p += 256;

    const int NB = (NN + SCAN_B - 1) / SCAN_B;   // 49

    hipMemsetAsync(dinv,   0, (size_t)NN * 4, stream);
    hipMemsetAsync(counts, 0, (size_t)NN * 4, stream);

    k_deg_count<<<(NE + 255) / 256, 256, 0, stream>>>(edst, ew, dinv, counts, NE);
    k_dinv<<<(NN + 255) / 256, 256, 0, stream>>>(dinv, NN);
    k_scan1<<<NB, SCAN_B, 0, stream>>>(counts, offs, bsums, NN);
    k_scan2<<<1, 64, 0, stream>>>(bsums, NB);
    k_scan3<<<(NN + 256) / 256, 256, 0, stream>>>(offs, bsums, cursor, NN, NE);
    k_fill<<<(NE + 255) / 256, 256, 0, stream>>>(esrc, edst, ew, dinv, cursor, src_s, norm_s, NE);

    // layer 1
    k_gemm128<<<(NN + 63) / 64, 256, 0, stream>>>(x, W1, xw, NN);
    k_agg128h<<<NN / 4, 256, 0, stream>>>(xw, dinv, offs, src_s, norm_s, b1, h, 1);
    // layer 2
    k_gemm128<<<(NN + 63) / 64, 256, 0, stream>>>(h, W2, xw, NN);
    k_agg128h<<<NN / 4, 256, 0, stream>>>(xw, dinv, offs, src_s, norm_s, b2, h, 1);
    // layer 3
    k_gemm16<<<(NN + 15) / 16, 256, 0, stream>>>(h, W3, xw3, NN);
    k_agg16_ls<<<NN / 16, 256, 0, stream>>>(xw3, dinv, offs, src_s, norm_s, b3, out);
}

// Round 3
// 293.294 us; speedup vs baseline: 1.3624x; 1.1145x over previous
//
#include <hip/hip_runtime.h>
#include <math.h>

#define NN 50000
#define NE 500000
#define NF 128
#define NO 16
#define SCAN_B 1024
#define NPART 16

typedef __attribute__((ext_vector_type(8))) _Float16 half8;

// ---------------- graph preprocessing (atomic-light CSR build) ----------------

// pass 1: per-edge rank within (partition, dst) via partitioned atomic counts
__global__ void k_count_rank(const int* __restrict__ dst, int* __restrict__ pcnt,
                             int* __restrict__ rank, int E) {
    int part = blockIdx.x & (NPART - 1);
    int e = blockIdx.x * blockDim.x + threadIdx.x;
    if (e < E) {
        int d = dst[e];
        rank[e] = atomicAdd(&pcnt[part * NN + d], 1);
    }
}

// pass 2: per-node: turn partition counts into partition bases (in place) + total
__global__ void k_combine(int* __restrict__ pcnt, int* __restrict__ counts, int N) {
    int n = blockIdx.x * blockDim.x + threadIdx.x;
    if (n < N) {
        int run = 0;
#pragma unroll
        for (int p = 0; p < NPART; ++p) {
            int v = pcnt[p * NN + n];
            pcnt[p * NN + n] = run;
            run += v;
        }
        counts[n] = run;
    }
}

// exclusive scan of counts -> offs (3-phase)
__global__ void k_scan1(const int* __restrict__ counts, int* __restrict__ offs,
                        int* __restrict__ bsums, int N) {
    __shared__ int s[SCAN_B];
    int t = threadIdx.x;
    int i = blockIdx.x * SCAN_B + t;
    int c = (i < N) ? counts[i] : 0;
    s[t] = c;
    __syncthreads();
    for (int off = 1; off < SCAN_B; off <<= 1) {
        int x = (t >= off) ? s[t - off] : 0;
        __syncthreads();
        s[t] += x;
        __syncthreads();
    }
    if (i < N) offs[i] = s[t] - c;            // exclusive within block
    if (t == SCAN_B - 1) bsums[blockIdx.x] = s[t];
}

__global__ void k_scan2(int* __restrict__ bsums, int NB) {
    if (threadIdx.x == 0 && blockIdx.x == 0) {
        int run = 0;
        for (int i = 0; i < NB; ++i) { int c = bsums[i]; bsums[i] = run; run += c; }
    }
}

__global__ void k_scan3(int* __restrict__ offs, const int* __restrict__ bsums,
                        int N, int E) {
    int i = blockIdx.x * blockDim.x + threadIdx.x;
    if (i < N) {
        offs[i] = offs[i] + bsums[i >> 10];
    } else if (i == N) {
        offs[N] = E;
    }
}

// pass 3: atomic-free scatter into CSR slots
__global__ void k_scatter(const int* __restrict__ src, const int* __restrict__ dst,
                          const float* __restrict__ ew, const int* __restrict__ offs,
                          const int* __restrict__ pcnt, const int* __restrict__ rank,
                          int* __restrict__ src_s, float* __restrict__ ew_s, int E) {
    int part = blockIdx.x & (NPART - 1);
    int e = blockIdx.x * blockDim.x + threadIdx.x;
    if (e < E) {
        int d = dst[e];
        int p = offs[d] + pcnt[part * NN + d] + rank[e];
        src_s[p] = src[e];
        ew_s[p]  = ew[e];
    }
}

// pass 4: deg from CSR (no atomics) -> dinv
__global__ void k_dinv_csr(const float* __restrict__ ew_s, const int* __restrict__ offs,
                           float* __restrict__ dinv, int N) {
    int n = blockIdx.x * blockDim.x + threadIdx.x;
    if (n < N) {
        float deg = 1.0f;                 // self-loop weight
        int s = offs[n], e = offs[n + 1];
        for (int j = s; j < e; ++j) deg += ew_s[j];
        dinv[n] = rsqrtf(deg);
    }
}

// pass 5: edge norms in CSR order
__global__ void k_norm_csr(const float* __restrict__ ew_s, const int* __restrict__ src_s,
                           const int* __restrict__ offs, const float* __restrict__ dinv,
                           float* __restrict__ norm_s, int N) {
    int n = blockIdx.x * blockDim.x + threadIdx.x;
    if (n < N) {
        float dn = dinv[n];
        int s = offs[n], e = offs[n + 1];
        for (int j = s; j < e; ++j)
            norm_s[j] = dinv[src_s[j]] * ew_s[j] * dn;
    }
}

// ---------------- GEMM: Y[M,128](fp16) = X[M,128](fp32) @ W[128,128] ----------------
__global__ __launch_bounds__(256) void k_gemm128(const float* __restrict__ X,
                                                 const float* __restrict__ W,
                                                 _Float16* __restrict__ Y, int M) {
    __shared__ float Xs[64][68];
    __shared__ float Ws[64][128];
    const int tid = threadIdx.x;
    const int tx = tid & 15;
    const int ty = tid >> 4;
    const int r0g = blockIdx.x * 64;

    float acc[4][8];
#pragma unroll
    for (int i = 0; i < 4; ++i)
#pragma unroll
        for (int j = 0; j < 8; ++j) acc[i][j] = 0.0f;

    for (int kc = 0; kc < 128; kc += 64) {
        {
            int rr = tid >> 4;
            int k4 = tid & 15;
#pragma unroll
            for (int it = 0; it < 4; ++it) {
                int row = it * 16 + rr;
                int grow = r0g + row; if (grow > M - 1) grow = M - 1;
                float4 v = *(const float4*)(X + (size_t)grow * NF + kc + k4 * 4);
                *(float4*)(&Xs[row][k4 * 4]) = v;
            }
        }
        {
            int kk0 = tid >> 5;
            int c4  = tid & 31;
#pragma unroll
            for (int it = 0; it < 8; ++it) {
                int kk = it * 8 + kk0;
                float4 v = *(const float4*)(W + (size_t)(kc + kk) * NF + c4 * 4);
                *(float4*)(&Ws[kk][c4 * 4]) = v;
            }
        }
        __syncthreads();

#pragma unroll 8
        for (int k = 0; k < 64; ++k) {
            float a0 = Xs[ty * 4 + 0][k];
            float a1 = Xs[ty * 4 + 1][k];
            float a2 = Xs[ty * 4 + 2][k];
            float a3 = Xs[ty * 4 + 3][k];
            float4 b0 = *(const float4*)(&Ws[k][tx * 8]);
            float4 b1 = *(const float4*)(&Ws[k][tx * 8 + 4]);
            float bb[8] = {b0.x, b0.y, b0.z, b0.w, b1.x, b1.y, b1.z, b1.w};
#pragma unroll
            for (int j = 0; j < 8; ++j) {
                acc[0][j] = fmaf(a0, bb[j], acc[0][j]);
                acc[1][j] = fmaf(a1, bb[j], acc[1][j]);
                acc[2][j] = fmaf(a2, bb[j], acc[2][j]);
                acc[3][j] = fmaf(a3, bb[j], acc[3][j]);
            }
        }
        __syncthreads();
    }

#pragma unroll
    for (int i = 0; i < 4; ++i) {
        int row = r0g + ty * 4 + i;
        if (row < M) {
            half8 hv;
#pragma unroll
            for (int j = 0; j < 8; ++j) hv[j] = (_Float16)acc[i][j];
            *(half8*)(Y + (size_t)row * NF + tx * 8) = hv;
        }
    }
}

// ---------------- aggregation, 128-wide, fp16 gather table ----------------
__global__ __launch_bounds__(256) void k_agg128h(const _Float16* __restrict__ xw,
                                                 const float* __restrict__ dinv,
                                                 const int* __restrict__ offs,
                                                 const int* __restrict__ src_s,
                                                 const float* __restrict__ norm_s,
                                                 const float* __restrict__ bias,
                                                 float* __restrict__ out, int relu) {
    const int tid = threadIdx.x;
    const int ln = tid & 63;
    int n = __builtin_amdgcn_readfirstlane(blockIdx.x * 4 + (tid >> 6));

    union CV { unsigned int u; _Float16 h[2]; };

    float di = dinv[n];
    CV sv; sv.u = *(const unsigned int*)(xw + (size_t)n * NF + ln * 2);
    float acc0 = (float)sv.h[0] * (di * di);
    float acc1 = (float)sv.h[1] * (di * di);

    int s = offs[n], e = offs[n + 1];
    int j = s;
    for (; j + 1 < e; j += 2) {
        int s0 = src_s[j], s1 = src_s[j + 1];
        float w0 = norm_s[j], w1 = norm_s[j + 1];
        CV u0, u1;
        u0.u = *(const unsigned int*)(xw + (size_t)s0 * NF + ln * 2);
        u1.u = *(const unsigned int*)(xw + (size_t)s1 * NF + ln * 2);
        acc0 = fmaf((float)u0.h[0], w0, acc0);
        acc1 = fmaf((float)u0.h[1], w0, acc1);
        acc0 = fmaf((float)u1.h[0], w1, acc0);
        acc1 = fmaf((float)u1.h[1], w1, acc1);
    }
    if (j < e) {
        int s0 = src_s[j];
        float w0 = norm_s[j];
        CV u0; u0.u = *(const unsigned int*)(xw + (size_t)s0 * NF + ln * 2);
        acc0 = fmaf((float)u0.h[0], w0, acc0);
        acc1 = fmaf((float)u0.h[1], w0, acc1);
    }
    acc0 += bias[ln * 2];
    acc1 += bias[ln * 2 + 1];
    if (relu) { acc0 = fmaxf(acc0, 0.0f); acc1 = fmaxf(acc1, 0.0f); }
    float2 o = {acc0, acc1};
    *(float2*)(out + (size_t)n * NF + ln * 2) = o;
}

// ---------------- GEMM: Y[M,16] = H[M,128] @ W3[128,16] ----------------
__global__ __launch_bounds__(256) void k_gemm16(const float* __restrict__ H,
                                                const float* __restrict__ W3,
                                                float* __restrict__ Y, int M) {
    __shared__ float Wl[NF * NO];
    __shared__ float Hs[16 * 132];
    int tid = threadIdx.x;
    for (int i = tid; i < NF * NO; i += 256) Wl[i] = W3[i];
    int n0 = blockIdx.x * 16;
#pragma unroll
    for (int it = 0; it < 2; ++it) {
        int idx = tid + it * 256;
        int r = idx >> 5, f4 = idx & 31;
        int gr = n0 + r; if (gr > M - 1) gr = M - 1;
        *(float4*)(&Hs[r * 132 + f4 * 4]) = *(const float4*)(H + (size_t)gr * NF + f4 * 4);
    }
    __syncthreads();
    int ln = tid >> 4, c = tid & 15;
    float acc = 0.0f;
#pragma unroll 8
    for (int k = 0; k < NF; ++k) acc = fmaf(Hs[ln * 132 + k], Wl[k * NO + c], acc);
    int n = n0 + ln;
    if (n < M) Y[(size_t)n * NO + c] = acc;
}

// ---------------- final aggregation (16-wide) + bias + log_softmax ----------------
__global__ __launch_bounds__(256) void k_agg16_ls(const float* __restrict__ xw,
                                                  const float* __restrict__ dinv,
                                                  const int* __restrict__ offs,
                                                  const int* __restrict__ src_s,
                                                  const float* __restrict__ norm_s,
                                                  const float* __restrict__ bias,
                                                  float* __restrict__ out) {
    int tid = threadIdx.x;
    int ln = tid >> 4, c = tid & 15;
    int n = blockIdx.x * 16 + ln;
    float di = dinv[n];
    float acc = xw[(size_t)n * NO + c] * (di * di);
    int s = offs[n], e = offs[n + 1];
    for (int j = s; j < e; ++j) {
        acc = fmaf(xw[(size_t)src_s[j] * NO + c], norm_s[j], acc);
    }
    acc += bias[c];
    float m = acc;
#pragma unroll
    for (int off = 8; off > 0; off >>= 1) m = fmaxf(m, __shfl_xor(m, off, 16));
    float ex = expf(acc - m);
    float ss = ex;
#pragma unroll
    for (int off = 8; off > 0; off >>= 1) ss += __shfl_xor(ss, off, 16);
    out[(size_t)n * NO + c] = acc - m - logf(ss);
}

// ---------------- launch ----------------

extern "C" void kernel_launch(void* const* d_in, const int* in_sizes, int n_in,
                              void* d_out, int out_size, void* d_ws, size_t ws_size,
                              hipStream_t stream) {
    const float* x   = (const float*)d_in[0];
    const int*   esrc= (const int*)  d_in[1];
    const int*   edst= (const int*)  d_in[2];
    const float* ew  = (const float*)d_in[3];
    const float* W1  = (const float*)d_in[4];
    const float* b1  = (const float*)d_in[5];
    const float* W2  = (const float*)d_in[6];
    const float* b2  = (const float*)d_in[7];
    const float* W3  = (const float*)d_in[8];
    const float* b3  = (const float*)d_in[9];
    float* out = (float*)d_out;

    // workspace carve
    char* p = (char*)d_ws;
    _Float16* xw  = (_Float16*)p; p += (size_t)NN * NF * 2;  // 12.8 MB fp16
    float* h      = (float*)p; p += (size_t)NN * NF * 4;     // 25.6 MB
    float* xw3    = (float*)p; p += (size_t)NN * NO * 4;     // 3.2 MB
    float* dinv   = (float*)p; p += (size_t)NN * 4;
    float* norm_s = (float*)p; p += (size_t)NE * 4;
    int*   src_s  = (int*)p;   p += (size_t)NE * 4;
    float* ew_s   = (float*)p; p += (size_t)NE * 4;
    int*   rank   = (int*)p;   p += (size_t)NE * 4;
    int*   pcnt   = (int*)p;   p += (size_t)NPART * NN * 4;  // 3.2 MB
    int*   counts = (int*)p;   p += (size_t)NN * 4;
    int*   offs   = (int*)p;   p += (size_t)(NN + 1) * 4;
    int*   bsums  = (int*)p;   p += 256;

    const int NB  = (NN + SCAN_B - 1) / SCAN_B;   // 49
    const int EBL = (NE + 255) / 256;             // edge-parallel blocks
    const int NBL = (NN + 255) / 256;             // node-parallel blocks

    hipMemsetAsync(pcnt, 0, (size_t)NPART * NN * 4, stream);

    k_count_rank<<<EBL, 256, 0, stream>>>(edst, pcnt, rank, NE);
    k_combine<<<NBL, 256, 0, stream>>>(pcnt, counts, NN);
    k_scan1<<<NB, SCAN_B, 0, stream>>>(counts, offs, bsums, NN);
    k_scan2<<<1, 64, 0, stream>>>(bsums, NB);
    k_scan3<<<(NN + 256) / 256, 256, 0, stream>>>(offs, bsums, NN, NE);
    k_scatter<<<EBL, 256, 0, stream>>>(esrc, edst, ew, offs, pcnt, rank, src_s, ew_s, NE);
    k_dinv_csr<<<NBL, 256, 0, stream>>>(ew_s, offs, dinv, NN);
    k_norm_csr<<<NBL, 256, 0, stream>>>(ew_s, src_s, offs, dinv, norm_s, NN);

    // layer 1
    k_gemm128<<<(NN + 63) / 64, 256, 0, stream>>>(x, W1, xw, NN);
    k_agg128h<<<NN / 4, 256, 0, stream>>>(xw, dinv, offs, src_s, norm_s, b1, h, 1);
    // layer 2
    k_gemm128<<<(NN + 63) / 64, 256, 0, stream>>>(h, W2, xw, NN);
    k_agg128h<<<NN / 4, 256, 0, stream>>>(xw, dinv, offs, src_s, norm_s, b2, h, 1);
    // layer 3
    k_gemm16<<<(NN + 15) / 16, 256, 0, stream>>>(h, W3, xw3, NN);
    k_agg16_ls<<<NN / 16, 256, 0, stream>>>(xw3, dinv, offs, src_s, norm_s, b3, out);
}

// Round 4
// 266.669 us; speedup vs baseline: 1.4985x; 1.0998x over previous
//
#include <hip/hip_runtime.h>
#include <math.h>

#define NN 50000
#define NE 500000
#define NF 128
#define NO 16
#define SCAN_B 1024
#define NPART 16

typedef _Float16 f16x8 __attribute__((ext_vector_type(8)));
typedef float f32x4 __attribute__((ext_vector_type(4)));

// ---------------- graph preprocessing (atomic-light CSR build) ----------------

__global__ void k_count_rank(const int* __restrict__ dst, int* __restrict__ pcnt,
                             int* __restrict__ rank, int E) {
    int part = blockIdx.x & (NPART - 1);
    int e = blockIdx.x * blockDim.x + threadIdx.x;
    if (e < E) {
        int d = dst[e];
        rank[e] = atomicAdd(&pcnt[part * NN + d], 1);
    }
}

__global__ void k_combine(int* __restrict__ pcnt, int* __restrict__ counts, int N) {
    int n = blockIdx.x * blockDim.x + threadIdx.x;
    if (n < N) {
        int run = 0;
#pragma unroll
        for (int p = 0; p < NPART; ++p) {
            int v = pcnt[p * NN + n];
            pcnt[p * NN + n] = run;
            run += v;
        }
        counts[n] = run;
    }
}

__global__ void k_scan1(const int* __restrict__ counts, int* __restrict__ offs,
                        int* __restrict__ bsums, int N) {
    __shared__ int s[SCAN_B];
    int t = threadIdx.x;
    int i = blockIdx.x * SCAN_B + t;
    int c = (i < N) ? counts[i] : 0;
    s[t] = c;
    __syncthreads();
    for (int off = 1; off < SCAN_B; off <<= 1) {
        int x = (t >= off) ? s[t - off] : 0;
        __syncthreads();
        s[t] += x;
        __syncthreads();
    }
    if (i < N) offs[i] = s[t] - c;
    if (t == SCAN_B - 1) bsums[blockIdx.x] = s[t];
}

// 64-lane shuffle scan (NB=49 <= 64) -> exclusive block sums, no serial chain
__global__ void k_scan2(int* __restrict__ bsums, int NB) {
    int t = threadIdx.x;
    int v = (t < NB) ? bsums[t] : 0;
    int orig = v;
#pragma unroll
    for (int off = 1; off < 64; off <<= 1) {
        int u = __shfl_up(v, off, 64);
        if (t >= off) v += u;
    }
    if (t < NB) bsums[t] = v - orig;
}

__global__ void k_scan3(int* __restrict__ offs, const int* __restrict__ bsums,
                        int N, int E) {
    int i = blockIdx.x * blockDim.x + threadIdx.x;
    if (i < N) {
        offs[i] = offs[i] + bsums[i >> 10];
    } else if (i == N) {
        offs[N] = E;
    }
}

__global__ void k_scatter(const int* __restrict__ src, const int* __restrict__ dst,
                          const float* __restrict__ ew, const int* __restrict__ offs,
                          const int* __restrict__ pcnt, const int* __restrict__ rank,
                          int* __restrict__ src_s, float* __restrict__ ew_s, int E) {
    int part = blockIdx.x & (NPART - 1);
    int e = blockIdx.x * blockDim.x + threadIdx.x;
    if (e < E) {
        int d = dst[e];
        int p = offs[d] + pcnt[part * NN + d] + rank[e];
        src_s[p] = src[e];
        ew_s[p]  = ew[e];
    }
}

__global__ void k_dinv_csr(const float* __restrict__ ew_s, const int* __restrict__ offs,
                           float* __restrict__ dinv, int N) {
    int n = blockIdx.x * blockDim.x + threadIdx.x;
    if (n < N) {
        float deg = 1.0f;
        int s = offs[n], e = offs[n + 1];
        for (int j = s; j < e; ++j) deg += ew_s[j];
        dinv[n] = rsqrtf(deg);
    }
}

// transpose + fp16-convert both 128x128 weights: WT[n][k] = W[k][n]
__global__ void k_prep_w(const float* __restrict__ W1, const float* __restrict__ W2,
                         _Float16* __restrict__ W1T, _Float16* __restrict__ W2T) {
    int idx = blockIdx.x * 256 + threadIdx.x;   // grid 64 -> 16384
    int r = idx >> 7, c = idx & 127;
    W1T[(size_t)c * NF + r] = (_Float16)W1[idx];
    W2T[(size_t)c * NF + r] = (_Float16)W2[idx];
}

// ---------------- MFMA GEMM: Z[M,128](fp16) = dinv ⊙ (X[M,128] @ W) ----------------
// 256 thr = 4 waves; block tile 64 rows; wave w owns rows r0+w*16 .. +16, all 128 cols.
// A-frag loaded straight from global (layer1: fp32->fp16 in-register).
// B-frag from pre-transposed fp16 WT (16B contiguous per lane).

__device__ inline f16x8 afrag_load(const float* X, int row, int k0) {
    const float4* p = (const float4*)(X + (size_t)row * NF + k0);
    float4 a = p[0], b = p[1];
    f16x8 r;
    r[0] = (_Float16)a.x; r[1] = (_Float16)a.y; r[2] = (_Float16)a.z; r[3] = (_Float16)a.w;
    r[4] = (_Float16)b.x; r[5] = (_Float16)b.y; r[6] = (_Float16)b.z; r[7] = (_Float16)b.w;
    return r;
}
__device__ inline f16x8 afrag_load(const _Float16* X, int row, int k0) {
    return *(const f16x8*)(X + (size_t)row * NF + k0);
}

template <typename TA>
__global__ __launch_bounds__(256) void k_gemm_mfma(const TA* __restrict__ X,
                                                   const _Float16* __restrict__ WT,
                                                   const float* __restrict__ dinv,
                                                   _Float16* __restrict__ Z, int M) {
    __shared__ _Float16 ls[4][16 * NF];       // per-wave epilogue repack, 4x4KB
    const int tid  = threadIdx.x;
    const int w    = tid >> 6;
    const int lane = tid & 63;
    const int n16  = lane & 15;
    const int quad = lane >> 4;
    const int r0   = blockIdx.x * 64 + w * 16;

    int arow = r0 + n16; if (arow > M - 1) arow = M - 1;

    f32x4 acc[8];
#pragma unroll
    for (int c = 0; c < 8; ++c) acc[c] = (f32x4){0.f, 0.f, 0.f, 0.f};

#pragma unroll
    for (int kk = 0; kk < 4; ++kk) {
        int k0 = kk * 32 + quad * 8;
        f16x8 a = afrag_load(X, arow, k0);
#pragma unroll
        for (int c = 0; c < 8; ++c) {
            f16x8 b = *(const f16x8*)(WT + (size_t)(c * 16 + n16) * NF + k0);
            acc[c] = __builtin_amdgcn_mfma_f32_16x16x32_f16(a, b, acc[c], 0, 0, 0);
        }
    }

    // epilogue: scale by dinv[row], fp16, repack via LDS for coalesced stores
#pragma unroll
    for (int reg = 0; reg < 4; ++reg) {
        int lrow = quad * 4 + reg;
        int grow = r0 + lrow; if (grow > M - 1) grow = M - 1;
        float di = dinv[grow];
#pragma unroll
        for (int c = 0; c < 8; ++c)
            ls[w][lrow * NF + c * 16 + n16] = (_Float16)(acc[c][reg] * di);
    }
    __syncthreads();
#pragma unroll
    for (int i = 0; i < 4; ++i) {
        int off16 = i * 64 + lane;            // 16B chunk index in this wave's buffer
        int row = off16 >> 4;
        int grow = r0 + row;
        if (grow < M) {
            f16x8 v = *(const f16x8*)(&ls[w][off16 * 8]);
            *(f16x8*)(Z + (size_t)grow * NF + (off16 & 15) * 8) = v;
        }
    }
}

// ---------------- aggregation, 128-wide: h = [relu](dinv_n*(z_n + sum ew*z_src) + b) ----------------
__global__ __launch_bounds__(256) void k_agg128h(const _Float16* __restrict__ z,
                                                 const float* __restrict__ dinv,
                                                 const int* __restrict__ offs,
                                                 const int* __restrict__ src_s,
                                                 const float* __restrict__ ew_s,
                                                 const float* __restrict__ bias,
                                                 _Float16* __restrict__ hout, int relu) {
    const int tid = threadIdx.x;
    const int ln = tid & 63;
    int n = __builtin_amdgcn_readfirstlane(blockIdx.x * 4 + (tid >> 6));

    union CV { unsigned int u; _Float16 h[2]; };

    float di = dinv[n];
    CV sv; sv.u = *(const unsigned int*)(z + (size_t)n * NF + ln * 2);
    float acc0 = (float)sv.h[0];
    float acc1 = (float)sv.h[1];

    int s = offs[n], e = offs[n + 1];
    int j = s;
    for (; j + 3 < e; j += 4) {
        int s0 = src_s[j], s1 = src_s[j + 1], s2 = src_s[j + 2], s3 = src_s[j + 3];
        float w0 = ew_s[j], w1 = ew_s[j + 1], w2 = ew_s[j + 2], w3 = ew_s[j + 3];
        CV u0, u1, u2, u3;
        u0.u = *(const unsigned int*)(z + (size_t)s0 * NF + ln * 2);
        u1.u = *(const unsigned int*)(z + (size_t)s1 * NF + ln * 2);
        u2.u = *(const unsigned int*)(z + (size_t)s2 * NF + ln * 2);
        u3.u = *(const unsigned int*)(z + (size_t)s3 * NF + ln * 2);
        acc0 = fmaf((float)u0.h[0], w0, acc0); acc1 = fmaf((float)u0.h[1], w0, acc1);
        acc0 = fmaf((float)u1.h[0], w1, acc0); acc1 = fmaf((float)u1.h[1], w1, acc1);
        acc0 = fmaf((float)u2.h[0], w2, acc0); acc1 = fmaf((float)u2.h[1], w2, acc1);
        acc0 = fmaf((float)u3.h[0], w3, acc0); acc1 = fmaf((float)u3.h[1], w3, acc1);
    }
    for (; j < e; ++j) {
        int s0 = src_s[j];
        float w0 = ew_s[j];
        CV u0; u0.u = *(const unsigned int*)(z + (size_t)s0 * NF + ln * 2);
        acc0 = fmaf((float)u0.h[0], w0, acc0);
        acc1 = fmaf((float)u0.h[1], w0, acc1);
    }
    float2 bb = *(const float2*)(bias + ln * 2);
    acc0 = fmaf(di, acc0, bb.x);
    acc1 = fmaf(di, acc1, bb.y);
    if (relu) { acc0 = fmaxf(acc0, 0.0f); acc1 = fmaxf(acc1, 0.0f); }
    CV o; o.h[0] = (_Float16)acc0; o.h[1] = (_Float16)acc1;
    *(unsigned int*)(hout + (size_t)n * NF + ln * 2) = o.u;
}

// ---------------- GEMM: Z3[M,16] = dinv ⊙ (H[M,128](fp16) @ W3[128,16]) ----------------
__global__ __launch_bounds__(256) void k_gemm16(const _Float16* __restrict__ H,
                                                const float* __restrict__ W3,
                                                const float* __restrict__ dinv,
                                                float* __restrict__ Z3, int M) {
    __shared__ float Wl[NF * NO];
    __shared__ float Hs[16 * 132];
    int tid = threadIdx.x;
    for (int i = tid; i < NF * NO; i += 256) Wl[i] = W3[i];
    int n0 = blockIdx.x * 16;
    {
        int row = tid >> 4, h8 = tid & 15;
        int gr = n0 + row; if (gr > M - 1) gr = M - 1;
        f16x8 v = *(const f16x8*)(H + (size_t)gr * NF + h8 * 8);
        float4 f0 = {(float)v[0], (float)v[1], (float)v[2], (float)v[3]};
        float4 f1 = {(float)v[4], (float)v[5], (float)v[6], (float)v[7]};
        *(float4*)(&Hs[row * 132 + h8 * 8])     = f0;
        *(float4*)(&Hs[row * 132 + h8 * 8 + 4]) = f1;
    }
    __syncthreads();
    int ln = tid >> 4, c = tid & 15;
    float acc = 0.0f;
#pragma unroll 8
    for (int k = 0; k < NF; ++k) acc = fmaf(Hs[ln * 132 + k], Wl[k * NO + c], acc);
    int n = n0 + ln;
    if (n < M) Z3[(size_t)n * NO + c] = acc * dinv[n];
}

// ---------------- final aggregation (16-wide) + bias + log_softmax ----------------
__global__ __launch_bounds__(256) void k_agg16_ls(const float* __restrict__ z3,
                                                  const float* __restrict__ dinv,
                                                  const int* __restrict__ offs,
                                                  const int* __restrict__ src_s,
                                                  const float* __restrict__ ew_s,
                                                  const float* __restrict__ bias,
                                                  float* __restrict__ out) {
    int tid = threadIdx.x;
    int ln = tid >> 4, c = tid & 15;
    int n = blockIdx.x * 16 + ln;
    float acc = z3[(size_t)n * NO + c];
    int s = offs[n], e = offs[n + 1];
    for (int j = s; j < e; ++j) {
        acc = fmaf(z3[(size_t)src_s[j] * NO + c], ew_s[j], acc);
    }
    acc = fmaf(dinv[n], acc, bias[c]);
    float m = acc;
#pragma unroll
    for (int off = 8; off > 0; off >>= 1) m = fmaxf(m, __shfl_xor(m, off, 16));
    float ex = expf(acc - m);
    float ss = ex;
#pragma unroll
    for (int off = 8; off > 0; off >>= 1) ss += __shfl_xor(ss, off, 16);
    out[(size_t)n * NO + c] = acc - m - logf(ss);
}

// ---------------- launch ----------------

extern "C" void kernel_launch(void* const* d_in, const int* in_sizes, int n_in,
                              void* d_out, int out_size, void* d_ws, size_t ws_size,
                              hipStream_t stream) {
    const float* x   = (const float*)d_in[0];
    const int*   esrc= (const int*)  d_in[1];
    const int*   edst= (const int*)  d_in[2];
    const float* ew  = (const float*)d_in[3];
    const float* W1  = (const float*)d_in[4];
    const float* b1  = (const float*)d_in[5];
    const float* W2  = (const float*)d_in[6];
    const float* b2  = (const float*)d_in[7];
    const float* W3  = (const float*)d_in[8];
    const float* b3  = (const float*)d_in[9];
    float* out = (float*)d_out;

    // workspace carve
    char* p = (char*)d_ws;
    _Float16* z   = (_Float16*)p; p += (size_t)NN * NF * 2;   // 12.8 MB
    _Float16* h   = (_Float16*)p; p += (size_t)NN * NF * 2;   // 12.8 MB
    float* z3     = (float*)p; p += (size_t)NN * NO * 4;      // 3.2 MB
    float* dinv   = (float*)p; p += (size_t)NN * 4;
    float* ew_s   = (float*)p; p += (size_t)NE * 4;
    int*   src_s  = (int*)p;   p += (size_t)NE * 4;
    int*   rank   = (int*)p;   p += (size_t)NE * 4;
    int*   pcnt   = (int*)p;   p += (size_t)NPART * NN * 4;   // 3.2 MB
    int*   counts = (int*)p;   p += (size_t)NN * 4;
    int*   offs   = (int*)p;   p += (size_t)(NN + 1) * 4;
    int*   bsums  = (int*)p;   p += 256;
    _Float16* W1T = (_Float16*)p; p += (size_t)NF * NF * 2;
    _Float16* W2T = (_Float16*)p; p += (size_t)NF * NF * 2;

    const int NB  = (NN + SCAN_B - 1) / SCAN_B;   // 49
    const int EBL = (NE + 255) / 256;
    const int NBL = (NN + 255) / 256;

    hipMemsetAsync(pcnt, 0, (size_t)NPART * NN * 4, stream);

    k_count_rank<<<EBL, 256, 0, stream>>>(edst, pcnt, rank, NE);
    k_combine<<<NBL, 256, 0, stream>>>(pcnt, counts, NN);
    k_scan1<<<NB, SCAN_B, 0, stream>>>(counts, offs, bsums, NN);
    k_scan2<<<1, 64, 0, stream>>>(bsums, NB);
    k_scan3<<<(NN + 256) / 256, 256, 0, stream>>>(offs, bsums, NN, NE);
    k_scatter<<<EBL, 256, 0, stream>>>(esrc, edst, ew, offs, pcnt, rank, src_s, ew_s, NE);
    k_dinv_csr<<<NBL, 256, 0, stream>>>(ew_s, offs, dinv, NN);
    k_prep_w<<<64, 256, 0, stream>>>(W1, W2, W1T, W2T);

    // layer 1
    k_gemm_mfma<float><<<(NN + 63) / 64, 256, 0, stream>>>(x, W1T, dinv, z, NN);
    k_agg128h<<<NN / 4, 256, 0, stream>>>(z, dinv, offs, src_s, ew_s, b1, h, 1);
    // layer 2
    k_gemm_mfma<_Float16><<<(NN + 63) / 64, 256, 0, stream>>>(h, W2T, dinv, z, NN);
    k_agg128h<<<NN / 4, 256, 0, stream>>>(z, dinv, offs, src_s, ew_s, b2, h, 1);
    // layer 3
    k_gemm16<<<(NN + 15) / 16, 256, 0, stream>>>(h, W3, dinv, z3, NN);
    k_agg16_ls<<<NN / 16, 256, 0, stream>>>(z3, dinv, offs, src_s, ew_s, b3, out);
}

// Round 5
// 252.341 us; speedup vs baseline: 1.5835x; 1.0568x over previous
//
#include <hip/hip_runtime.h>
#include <math.h>

#define NN 50000
#define NE 500000
#define NF 128
#define NO 16
#define SCAN_B 1024
#define NPART 16
#define EBL 1954   // (NE+255)/256

typedef _Float16 f16x8 __attribute__((ext_vector_type(8)));
typedef float f32x4 __attribute__((ext_vector_type(4)));

// ---------------- graph preprocessing (atomic-light CSR build) ----------------

// pass 1: per-edge rank within (partition, dst); spare blocks transpose W1/W2 to fp16
__global__ void k_count_rank(const int* __restrict__ dst, int* __restrict__ pcnt,
                             int* __restrict__ rank, int E,
                             const float* __restrict__ W1, const float* __restrict__ W2,
                             _Float16* __restrict__ W1T, _Float16* __restrict__ W2T) {
    int b = blockIdx.x;
    if (b < EBL) {
        int part = b & (NPART - 1);
        int e = b * 256 + threadIdx.x;
        if (e < E) {
            int d = dst[e];
            rank[e] = atomicAdd(&pcnt[part * NN + d], 1);
        }
    } else {
        int idx = (b - EBL) * 256 + threadIdx.x;   // [0,16384)
        int r = idx >> 7, c = idx & 127;
        W1T[(size_t)c * NF + r] = (_Float16)W1[idx];
        W2T[(size_t)c * NF + r] = (_Float16)W2[idx];
    }
}

// pass 2: per-node partition bases (in place) + block-level exclusive scan of totals
__global__ void k_scan1f(int* __restrict__ pcnt, int* __restrict__ offs_p,
                         int* __restrict__ bsums, int N) {
    __shared__ int sm[SCAN_B];
    int t = threadIdx.x;
    int i = blockIdx.x * SCAN_B + t;
    int c = 0;
    if (i < N) {
        int run = 0;
#pragma unroll
        for (int p = 0; p < NPART; ++p) {
            int v = pcnt[p * NN + i];
            pcnt[p * NN + i] = run;
            run += v;
        }
        c = run;
    }
    sm[t] = c;
    __syncthreads();
    for (int off = 1; off < SCAN_B; off <<= 1) {
        int x = (t >= off) ? sm[t - off] : 0;
        __syncthreads();
        sm[t] += x;
        __syncthreads();
    }
    if (i < N) offs_p[i] = sm[t] - c;
    if (t == SCAN_B - 1) bsums[blockIdx.x] = sm[t];
}

// 64-lane shuffle scan (NB=49 <= 64) -> exclusive block sums
__global__ void k_scan2(int* __restrict__ bsums, int NB) {
    int t = threadIdx.x;
    int v = (t < NB) ? bsums[t] : 0;
    int orig = v;
#pragma unroll
    for (int off = 1; off < 64; off <<= 1) {
        int u = __shfl_up(v, off, 64);
        if (t >= off) v += u;
    }
    if (t < NB) bsums[t] = v - orig;
}

// pass 3: finalize offs, and fold node offset into every partition base
__global__ void k_scan3x(const int* __restrict__ offs_p, const int* __restrict__ bsums,
                         int* __restrict__ pcnt, int* __restrict__ offs_f, int E) {
    int i = blockIdx.x * blockDim.x + threadIdx.x;
    if (i < NPART * NN) {
        int p = i / NN;
        int n = i - p * NN;
        int v = offs_p[n] + bsums[n >> 10];
        pcnt[i] += v;
        if (p == 0) offs_f[n] = v;
    } else if (i == NPART * NN) {
        offs_f[NN] = E;
    }
}

// pass 4: atomic-free scatter of packed {src, ew} records
__global__ void k_scatter(const int* __restrict__ src, const int* __restrict__ dst,
                          const float* __restrict__ ew, const int* __restrict__ pcnt,
                          const int* __restrict__ rank, int2* __restrict__ edge_rec, int E) {
    int part = blockIdx.x & (NPART - 1);
    int e = blockIdx.x * blockDim.x + threadIdx.x;
    if (e < E) {
        int d = dst[e];
        int pos = pcnt[part * NN + d] + rank[e];
        int2 r;
        r.x = src[e];
        r.y = __float_as_int(ew[e]);
        edge_rec[pos] = r;
    }
}

// pass 5: deg from CSR -> dinv
__global__ void k_dinv_csr(const int2* __restrict__ edge_rec, const int* __restrict__ offs,
                           float* __restrict__ dinv, int N) {
    int n = blockIdx.x * blockDim.x + threadIdx.x;
    if (n < N) {
        float deg = 1.0f;
        int s = offs[n], e = offs[n + 1];
        for (int j = s; j < e; ++j) deg += __int_as_float(edge_rec[j].y);
        dinv[n] = rsqrtf(deg);
    }
}

// ---------------- MFMA GEMM: Z[M,128](fp16) = dinv ⊙ (X[M,128] @ W) ----------------

__device__ inline f16x8 afrag_load(const float* X, int row, int k0) {
    const float4* p = (const float4*)(X + (size_t)row * NF + k0);
    float4 a = p[0], b = p[1];
    f16x8 r;
    r[0] = (_Float16)a.x; r[1] = (_Float16)a.y; r[2] = (_Float16)a.z; r[3] = (_Float16)a.w;
    r[4] = (_Float16)b.x; r[5] = (_Float16)b.y; r[6] = (_Float16)b.z; r[7] = (_Float16)b.w;
    return r;
}
__device__ inline f16x8 afrag_load(const _Float16* X, int row, int k0) {
    return *(const f16x8*)(X + (size_t)row * NF + k0);
}

template <typename TA>
__global__ __launch_bounds__(256) void k_gemm_mfma(const TA* __restrict__ X,
                                                   const _Float16* __restrict__ WT,
                                                   const float* __restrict__ dinv,
                                                   _Float16* __restrict__ Z, int M) {
    __shared__ _Float16 ls[4][16 * NF];
    const int tid  = threadIdx.x;
    const int w    = tid >> 6;
    const int lane = tid & 63;
    const int n16  = lane & 15;
    const int quad = lane >> 4;
    const int r0   = blockIdx.x * 64 + w * 16;

    int arow = r0 + n16; if (arow > M - 1) arow = M - 1;

    f32x4 acc[8];
#pragma unroll
    for (int c = 0; c < 8; ++c) acc[c] = (f32x4){0.f, 0.f, 0.f, 0.f};

#pragma unroll
    for (int kk = 0; kk < 4; ++kk) {
        int k0 = kk * 32 + quad * 8;
        f16x8 a = afrag_load(X, arow, k0);
#pragma unroll
        for (int c = 0; c < 8; ++c) {
            f16x8 b = *(const f16x8*)(WT + (size_t)(c * 16 + n16) * NF + k0);
            acc[c] = __builtin_amdgcn_mfma_f32_16x16x32_f16(a, b, acc[c], 0, 0, 0);
        }
    }

#pragma unroll
    for (int reg = 0; reg < 4; ++reg) {
        int lrow = quad * 4 + reg;
        int grow = r0 + lrow; if (grow > M - 1) grow = M - 1;
        float di = dinv[grow];
#pragma unroll
        for (int c = 0; c < 8; ++c)
            ls[w][lrow * NF + c * 16 + n16] = (_Float16)(acc[c][reg] * di);
    }
    __syncthreads();
#pragma unroll
    for (int i = 0; i < 4; ++i) {
        int off16 = i * 64 + lane;
        int row = off16 >> 4;
        int grow = r0 + row;
        if (grow < M) {
            f16x8 v = *(const f16x8*)(&ls[w][off16 * 8]);
            *(f16x8*)(Z + (size_t)grow * NF + (off16 & 15) * 8) = v;
        }
    }
}

// ---------------- aggregation, 128-wide ----------------
// 1 wave per node; coalesced 8B edge-record loads + shfl broadcast; 4 gathers in flight.
__global__ __launch_bounds__(256) void k_agg128h(const _Float16* __restrict__ z,
                                                 const float* __restrict__ dinv,
                                                 const int* __restrict__ offs,
                                                 const int2* __restrict__ edge_rec,
                                                 const float* __restrict__ bias,
                                                 _Float16* __restrict__ hout, int relu) {
    const int tid = threadIdx.x;
    const int ln = tid & 63;
    int n = __builtin_amdgcn_readfirstlane(blockIdx.x * 4 + (tid >> 6));

    union CV { unsigned int u; _Float16 h[2]; };

    float di = dinv[n];
    CV sv; sv.u = *(const unsigned int*)(z + ((size_t)n << 7) + ln * 2);
    float acc0 = (float)sv.h[0];
    float acc1 = (float)sv.h[1];

    int s = offs[n], e = offs[n + 1];
    for (int base = s; base < e; base += 64) {
        int cnt = e - base; if (cnt > 64) cnt = 64;
        int2 rec = {0, 0};
        if (ln < cnt) rec = edge_rec[base + ln];
        int   my_s = rec.x;
        float my_w = __int_as_float(rec.y);
        int k = 0;
        for (; k + 3 < cnt; k += 4) {
            int s0 = __shfl(my_s, k, 64),     s1 = __shfl(my_s, k + 1, 64);
            int s2 = __shfl(my_s, k + 2, 64), s3 = __shfl(my_s, k + 3, 64);
            float w0 = __shfl(my_w, k, 64),     w1 = __shfl(my_w, k + 1, 64);
            float w2 = __shfl(my_w, k + 2, 64), w3 = __shfl(my_w, k + 3, 64);
            CV u0, u1, u2, u3;
            u0.u = *(const unsigned int*)(z + ((size_t)s0 << 7) + ln * 2);
            u1.u = *(const unsigned int*)(z + ((size_t)s1 << 7) + ln * 2);
            u2.u = *(const unsigned int*)(z + ((size_t)s2 << 7) + ln * 2);
            u3.u = *(const unsigned int*)(z + ((size_t)s3 << 7) + ln * 2);
            acc0 = fmaf((float)u0.h[0], w0, acc0); acc1 = fmaf((float)u0.h[1], w0, acc1);
            acc0 = fmaf((float)u1.h[0], w1, acc0); acc1 = fmaf((float)u1.h[1], w1, acc1);
            acc0 = fmaf((float)u2.h[0], w2, acc0); acc1 = fmaf((float)u2.h[1], w2, acc1);
            acc0 = fmaf((float)u3.h[0], w3, acc0); acc1 = fmaf((float)u3.h[1], w3, acc1);
        }
        for (; k < cnt; ++k) {
            int   s0 = __shfl(my_s, k, 64);
            float w0 = __shfl(my_w, k, 64);
            CV u0; u0.u = *(const unsigned int*)(z + ((size_t)s0 << 7) + ln * 2);
            acc0 = fmaf((float)u0.h[0], w0, acc0);
            acc1 = fmaf((float)u0.h[1], w0, acc1);
        }
    }
    float2 bb = *(const float2*)(bias + ln * 2);
    acc0 = fmaf(di, acc0, bb.x);
    acc1 = fmaf(di, acc1, bb.y);
    if (relu) { acc0 = fmaxf(acc0, 0.0f); acc1 = fmaxf(acc1, 0.0f); }
    CV o; o.h[0] = (_Float16)acc0; o.h[1] = (_Float16)acc1;
    *(unsigned int*)(hout + ((size_t)n << 7) + ln * 2) = o.u;
}

// ---------------- GEMM: Z3[M,16](fp16) = dinv ⊙ (H[M,128](fp16) @ W3[128,16]) ----------------
__global__ __launch_bounds__(256) void k_gemm16(const _Float16* __restrict__ H,
                                                const float* __restrict__ W3,
                                                const float* __restrict__ dinv,
                                                _Float16* __restrict__ Z3, int M) {
    __shared__ float Wl[NF * NO];
    __shared__ float Hs[16 * 132];
    int tid = threadIdx.x;
    for (int i = tid; i < NF * NO; i += 256) Wl[i] = W3[i];
    int n0 = blockIdx.x * 16;
    {
        int row = tid >> 4, h8 = tid & 15;
        int gr = n0 + row; if (gr > M - 1) gr = M - 1;
        f16x8 v = *(const f16x8*)(H + (size_t)gr * NF + h8 * 8);
        float4 f0 = {(float)v[0], (float)v[1], (float)v[2], (float)v[3]};
        float4 f1 = {(float)v[4], (float)v[5], (float)v[6], (float)v[7]};
        *(float4*)(&Hs[row * 132 + h8 * 8])     = f0;
        *(float4*)(&Hs[row * 132 + h8 * 8 + 4]) = f1;
    }
    __syncthreads();
    int ln = tid >> 4, c = tid & 15;
    float acc = 0.0f;
#pragma unroll 8
    for (int k = 0; k < NF; ++k) acc = fmaf(Hs[ln * 132 + k], Wl[k * NO + c], acc);
    int n = n0 + ln;
    if (n < M) Z3[(size_t)n * NO + c] = (_Float16)(acc * dinv[n]);
}

// ---------------- final aggregation (16-wide, fp16 table) + bias + log_softmax ----------------
__global__ __launch_bounds__(256) void k_agg16_ls(const _Float16* __restrict__ z3,
                                                  const float* __restrict__ dinv,
                                                  const int* __restrict__ offs,
                                                  const int2* __restrict__ edge_rec,
                                                  const float* __restrict__ bias,
                                                  float* __restrict__ out) {
    int tid = threadIdx.x;
    int ln = tid >> 4, c = tid & 15;
    int n = blockIdx.x * 16 + ln;
    float acc = (float)z3[(size_t)n * NO + c];
    int s = offs[n], e = offs[n + 1];
    int j = s;
    for (; j + 1 < e; j += 2) {
        int2 r0 = edge_rec[j], r1 = edge_rec[j + 1];
        acc = fmaf((float)z3[((size_t)r0.x << 4) + c], __int_as_float(r0.y), acc);
        acc = fmaf((float)z3[((size_t)r1.x << 4) + c], __int_as_float(r1.y), acc);
    }
    if (j < e) {
        int2 r0 = edge_rec[j];
        acc = fmaf((float)z3[((size_t)r0.x << 4) + c], __int_as_float(r0.y), acc);
    }
    acc = fmaf(dinv[n], acc, bias[c]);
    float m = acc;
#pragma unroll
    for (int off = 8; off > 0; off >>= 1) m = fmaxf(m, __shfl_xor(m, off, 16));
    float ex = expf(acc - m);
    float ss = ex;
#pragma unroll
    for (int off = 8; off > 0; off >>= 1) ss += __shfl_xor(ss, off, 16);
    out[(size_t)n * NO + c] = acc - m - logf(ss);
}

// ---------------- launch ----------------

extern "C" void kernel_launch(void* const* d_in, const int* in_sizes, int n_in,
                              void* d_out, int out_size, void* d_ws, size_t ws_size,
                              hipStream_t stream) {
    const float* x   = (const float*)d_in[0];
    const int*   esrc= (const int*)  d_in[1];
    const int*   edst= (const int*)  d_in[2];
    const float* ew  = (const float*)d_in[3];
    const float* W1  = (const float*)d_in[4];
    const float* b1  = (const float*)d_in[5];
    const float* W2  = (const float*)d_in[6];
    const float* b2  = (const float*)d_in[7];
    const float* W3  = (const float*)d_in[8];
    const float* b3  = (const float*)d_in[9];
    float* out = (float*)d_out;

    // workspace carve (8B alignment maintained for edge_rec)
    char* p = (char*)d_ws;
    _Float16* z   = (_Float16*)p; p += (size_t)NN * NF * 2;   // 12.8 MB
    _Float16* h   = (_Float16*)p; p += (size_t)NN * NF * 2;   // 12.8 MB
    _Float16* z3  = (_Float16*)p; p += (size_t)NN * NO * 2;   // 1.6 MB
    float* dinv   = (float*)p; p += (size_t)NN * 4;           // 0.2 MB
    int2*  edge_rec = (int2*)p; p += (size_t)NE * 8;          // 4 MB
    int*   rank   = (int*)p;   p += (size_t)NE * 4;           // 2 MB
    int*   pcnt   = (int*)p;   p += (size_t)NPART * NN * 4;   // 3.2 MB
    int*   offs_p = (int*)p;   p += (size_t)(NN + 1) * 4;
    int*   offs_f = (int*)p;   p += (size_t)(NN + 1) * 4;
    int*   bsums  = (int*)p;   p += 256;
    _Float16* W1T = (_Float16*)p; p += (size_t)NF * NF * 2;
    _Float16* W2T = (_Float16*)p; p += (size_t)NF * NF * 2;

    const int NB  = (NN + SCAN_B - 1) / SCAN_B;   // 49
    const int NBL = (NN + 255) / 256;

    hipMemsetAsync(pcnt, 0, (size_t)NPART * NN * 4, stream);

    k_count_rank<<<EBL + 64, 256, 0, stream>>>(edst, pcnt, rank, NE, W1, W2, W1T, W2T);
    k_scan1f<<<NB, SCAN_B, 0, stream>>>(pcnt, offs_p, bsums, NN);
    k_scan2<<<1, 64, 0, stream>>>(bsums, NB);
    k_scan3x<<<(NPART * NN + 256) / 256, 256, 0, stream>>>(offs_p, bsums, pcnt, offs_f, NE);
    k_scatter<<<EBL, 256, 0, stream>>>(esrc, edst, ew, pcnt, rank, edge_rec, NE);
    k_dinv_csr<<<NBL, 256, 0, stream>>>(edge_rec, offs_f, dinv, NN);

    // layer 1
    k_gemm_mfma<float><<<(NN + 63) / 64, 256, 0, stream>>>(x, W1T, dinv, z, NN);
    k_agg128h<<<NN / 4, 256, 0, stream>>>(z, dinv, offs_f, edge_rec, b1, h, 1);
    // layer 2
    k_gemm_mfma<_Float16><<<(NN + 63) / 64, 256, 0, stream>>>(h, W2T, dinv, z, NN);
    k_agg128h<<<NN / 4, 256, 0, stream>>>(z, dinv, offs_f, edge_rec, b2, h, 1);
    // layer 3
    k_gemm16<<<(NN + 15) / 16, 256, 0, stream>>>(h, W3, dinv, z3, NN);
    k_agg16_ls<<<NN / 16, 256, 0, stream>>>(z3, dinv, offs_f, edge_rec, b3, out);
}